// Round 4
// baseline (1596.564 us; speedup 1.0000x reference)
//
#include <hip/hip_runtime.h>
#include <math.h>

// Problem constants (B=16, S=2048, L=E=512, N=2048)
#define BS_TOK 32768
#define DIM 512
#define NCODE 2048

typedef _Float16 f16x8 __attribute__((ext_vector_type(8)));
typedef _Float16 f16x4 __attribute__((ext_vector_type(4)));
typedef float f32x16 __attribute__((ext_vector_type(16)));

#define LDH 40  // halves per LDS row: 32 data + 8 pad = 80 B
// Sound filter margin: worst-case |hh - true_sim| <= 2^-10*sum|a||b| (<=1,
// Cauchy-Schwarz on unit vectors) + fp32 accum (~3e-5) => eps ~1.01e-3.
// MARGIN = 2.5e-3 >= 2*eps.
#define MARGIN 2.5e-3f

// ---------------- row L2 normalize + fp16 hi/lo split ----------------
__global__ __launch_bounds__(256) void k_rownorm_split(
    const float* __restrict__ in, _Float16* __restrict__ hi,
    _Float16* __restrict__ lo, int rstride) {
  const int r = blockIdx.x;
  const int t = threadIdx.x;
  const float* row = in + (size_t)r * DIM;
  float v0 = row[t];
  float v1 = row[t + 256];
  float s = v0 * v0 + v1 * v1;
#pragma unroll
  for (int off = 32; off > 0; off >>= 1) s += __shfl_down(s, off, 64);
  __shared__ float ls[4];
  if ((t & 63) == 0) ls[t >> 6] = s;
  __syncthreads();  // also fences: all global reads of this row are done
  float tot = ls[0] + ls[1] + ls[2] + ls[3];
  float sc = 1.0f / fmaxf(sqrtf(tot), 1e-12f);
  float x0 = v0 * sc, x1 = v1 * sc;
  _Float16 h0 = (_Float16)x0;
  _Float16 h1 = (_Float16)x1;
  _Float16 e0 = (_Float16)((x0 - (float)h0) * 2048.0f);
  _Float16 e1 = (_Float16)((x1 - (float)h1) * 2048.0f);
  _Float16* hrow = hi + (size_t)r * rstride;
  _Float16* lrow = lo + (size_t)r * rstride;
  hrow[t] = h0;
  hrow[t + 256] = h1;
  lrow[t] = e0;
  lrow[t + 256] = e1;
}

// ---------------- fp32 -> fp16 hi/lo elementwise split (weights) ------
__global__ __launch_bounds__(256) void k_split_w(const float* __restrict__ w,
                                                 _Float16* __restrict__ hi,
                                                 _Float16* __restrict__ lo) {
  int t = (blockIdx.x * 256 + threadIdx.x) * 4;
  float4 v = *(const float4*)(w + t);
  f16x4 h, l;
  h.x = (_Float16)v.x; l.x = (_Float16)((v.x - (float)h.x) * 2048.0f);
  h.y = (_Float16)v.y; l.y = (_Float16)((v.y - (float)h.y) * 2048.0f);
  h.z = (_Float16)v.z; l.z = (_Float16)((v.z - (float)h.z) * 2048.0f);
  h.w = (_Float16)v.w; l.w = (_Float16)((v.w - (float)h.w) * 2048.0f);
  *(f16x4*)(hi + t) = h;
  *(f16x4*)(lo + t) = l;
}

// ---------------- MFMA split GEMM: input projection -------------------
__global__ __launch_bounds__(256, 2) void k_gemm_mfma_in(
    const float* __restrict__ A, const _Float16* __restrict__ Bhi,
    const _Float16* __restrict__ Blo, const float* __restrict__ bias,
    float* __restrict__ C) {
  __shared__ __align__(16) _Float16 sm[4 * 128 * LDH];  // 40960 B
  _Float16* sAh = sm;
  _Float16* sAl = sm + 128 * LDH;
  _Float16* sBh = sm + 2 * 128 * LDH;
  _Float16* sBl = sm + 3 * 128 * LDH;
  const int tid = threadIdx.x;
  const int w = tid >> 6, l = tid & 63;
  const int wm = w >> 1, wn = w & 1;
  const int lm = l & 31, lh = l >> 5;
  const int m0 = blockIdx.y * 128;
  const int n0 = blockIdx.x * 128;
  f32x16 aHH[2][2], aX[2][2];
#pragma unroll
  for (int mb = 0; mb < 2; ++mb)
#pragma unroll
    for (int nb = 0; nb < 2; ++nb) {
      aHH[mb][nb] = (f32x16)0.0f;
      aX[mb][nb] = (f32x16)0.0f;
    }
  for (int ks = 0; ks < DIM; ks += 32) {
    __syncthreads();
#pragma unroll
    for (int i = 0; i < 4; ++i) {
      int lin = tid + i * 256;
      int row = lin >> 3;
      int c4 = (lin & 7) << 2;
      float4 v = *(const float4*)(A + (size_t)(m0 + row) * DIM + ks + c4);
      f16x4 h, lo4;
      h.x = (_Float16)v.x; lo4.x = (_Float16)((v.x - (float)h.x) * 2048.0f);
      h.y = (_Float16)v.y; lo4.y = (_Float16)((v.y - (float)h.y) * 2048.0f);
      h.z = (_Float16)v.z; lo4.z = (_Float16)((v.z - (float)h.z) * 2048.0f);
      h.w = (_Float16)v.w; lo4.w = (_Float16)((v.w - (float)h.w) * 2048.0f);
      *(f16x4*)(&sAh[row * LDH + c4]) = h;
      *(f16x4*)(&sAl[row * LDH + c4]) = lo4;
    }
#pragma unroll
    for (int i = 0; i < 2; ++i) {
      int lin = tid + i * 256;
      int row = lin >> 2;
      int q = (lin & 3) * 8;
      const size_t g = (size_t)(n0 + row) * DIM + ks + q;
      *(f16x8*)(&sBh[row * LDH + q]) = *(const f16x8*)(Bhi + g);
      *(f16x8*)(&sBl[row * LDH + q]) = *(const f16x8*)(Blo + g);
    }
    __syncthreads();
#pragma unroll
    for (int c = 0; c < 2; ++c) {
      const int ko = c * 16 + lh * 8;
      f16x8 ah[2], al[2], bh[2], bl[2];
#pragma unroll
      for (int mb = 0; mb < 2; ++mb) {
        int r = wm * 64 + mb * 32 + lm;
        ah[mb] = *(const f16x8*)(&sAh[r * LDH + ko]);
        al[mb] = *(const f16x8*)(&sAl[r * LDH + ko]);
      }
#pragma unroll
      for (int nb = 0; nb < 2; ++nb) {
        int r = wn * 64 + nb * 32 + lm;
        bh[nb] = *(const f16x8*)(&sBh[r * LDH + ko]);
        bl[nb] = *(const f16x8*)(&sBl[r * LDH + ko]);
      }
#pragma unroll
      for (int mb = 0; mb < 2; ++mb)
#pragma unroll
        for (int nb = 0; nb < 2; ++nb) {
          aHH[mb][nb] = __builtin_amdgcn_mfma_f32_32x32x16_f16(
              ah[mb], bh[nb], aHH[mb][nb], 0, 0, 0);
          aX[mb][nb] = __builtin_amdgcn_mfma_f32_32x32x16_f16(
              ah[mb], bl[nb], aX[mb][nb], 0, 0, 0);
          aX[mb][nb] = __builtin_amdgcn_mfma_f32_32x32x16_f16(
              al[mb], bh[nb], aX[mb][nb], 0, 0, 0);
        }
    }
  }
#pragma unroll
  for (int nb = 0; nb < 2; ++nb) {
    int n = n0 + wn * 64 + nb * 32 + lm;
    float bv = bias[n];
#pragma unroll
    for (int mb = 0; mb < 2; ++mb)
#pragma unroll
      for (int r = 0; r < 16; ++r) {
        int m = m0 + wm * 64 + mb * 32 + (r & 3) + 8 * (r >> 2) + 4 * lh;
        C[(size_t)m * DIM + n] =
            aHH[mb][nb][r] + aX[mb][nb][r] * (1.0f / 2048.0f) + bv;
      }
  }
}

// ---------------- MFMA split GEMM: gathered output projection ---------
__global__ __launch_bounds__(256, 2) void k_gemm_mfma_gather(
    const _Float16* __restrict__ Ahi, const _Float16* __restrict__ Alo,
    const _Float16* __restrict__ Bhi, const _Float16* __restrict__ Blo,
    const float* __restrict__ bias, float* __restrict__ C,
    const int* __restrict__ gather, const float* __restrict__ zin) {
  __shared__ __align__(16) _Float16 sm[4 * 128 * LDH];
  __shared__ int gidx[128];
  _Float16* sAh = sm;
  _Float16* sAl = sm + 128 * LDH;
  _Float16* sBh = sm + 2 * 128 * LDH;
  _Float16* sBl = sm + 3 * 128 * LDH;
  const int tid = threadIdx.x;
  const int w = tid >> 6, l = tid & 63;
  const int wm = w >> 1, wn = w & 1;
  const int lm = l & 31, lh = l >> 5;
  const int m0 = blockIdx.y * 128;
  const int n0 = blockIdx.x * 128;
  if (tid < 128) gidx[tid] = gather[m0 + tid];
  f32x16 aHH[2][2], aX[2][2];
#pragma unroll
  for (int mb = 0; mb < 2; ++mb)
#pragma unroll
    for (int nb = 0; nb < 2; ++nb) {
      aHH[mb][nb] = (f32x16)0.0f;
      aX[mb][nb] = (f32x16)0.0f;
    }
  for (int ks = 0; ks < DIM; ks += 32) {
    __syncthreads();  // first iter also fences gidx
#pragma unroll
    for (int i = 0; i < 2; ++i) {
      int lin = tid + i * 256;
      int row = lin >> 2;
      int q = (lin & 3) * 8;
      const size_t ga = (size_t)gidx[row] * DIM + ks + q;
      *(f16x8*)(&sAh[row * LDH + q]) = *(const f16x8*)(Ahi + ga);
      *(f16x8*)(&sAl[row * LDH + q]) = *(const f16x8*)(Alo + ga);
      const size_t gb = (size_t)(n0 + row) * DIM + ks + q;
      *(f16x8*)(&sBh[row * LDH + q]) = *(const f16x8*)(Bhi + gb);
      *(f16x8*)(&sBl[row * LDH + q]) = *(const f16x8*)(Blo + gb);
    }
    __syncthreads();
#pragma unroll
    for (int c = 0; c < 2; ++c) {
      const int ko = c * 16 + lh * 8;
      f16x8 ah[2], al[2], bh[2], bl[2];
#pragma unroll
      for (int mb = 0; mb < 2; ++mb) {
        int r = wm * 64 + mb * 32 + lm;
        ah[mb] = *(const f16x8*)(&sAh[r * LDH + ko]);
        al[mb] = *(const f16x8*)(&sAl[r * LDH + ko]);
      }
#pragma unroll
      for (int nb = 0; nb < 2; ++nb) {
        int r = wn * 64 + nb * 32 + lm;
        bh[nb] = *(const f16x8*)(&sBh[r * LDH + ko]);
        bl[nb] = *(const f16x8*)(&sBl[r * LDH + ko]);
      }
#pragma unroll
      for (int mb = 0; mb < 2; ++mb)
#pragma unroll
        for (int nb = 0; nb < 2; ++nb) {
          aHH[mb][nb] = __builtin_amdgcn_mfma_f32_32x32x16_f16(
              ah[mb], bh[nb], aHH[mb][nb], 0, 0, 0);
          aX[mb][nb] = __builtin_amdgcn_mfma_f32_32x32x16_f16(
              ah[mb], bl[nb], aX[mb][nb], 0, 0, 0);
          aX[mb][nb] = __builtin_amdgcn_mfma_f32_32x32x16_f16(
              al[mb], bh[nb], aX[mb][nb], 0, 0, 0);
        }
    }
  }
#pragma unroll
  for (int nb = 0; nb < 2; ++nb) {
    int n = n0 + wn * 64 + nb * 32 + lm;
    float bv = bias[n];
#pragma unroll
    for (int mb = 0; mb < 2; ++mb)
#pragma unroll
      for (int r = 0; r < 16; ++r) {
        int m = m0 + wm * 64 + mb * 32 + (r & 3) + 8 * (r >> 2) + 4 * lh;
        float val = aHH[mb][nb][r] + aX[mb][nb][r] * (1.0f / 2048.0f) + bv;
        float zv = zin[(size_t)m * DIM + n];
        C[(size_t)m * DIM + n] = zv + (val - zv);
      }
  }
}

// ---------------- pass 1: hh-only similarity + candidate filter -------
// Block: 128 tokens x 1024 codes (grid 512 = 256 mtiles x 2 code-halves).
// Only the hi*hi MFMA term. Per (token, code-half, h_red) thread: running
// best + up to 4 candidates with v >= runbest - MARGIN (prune on new best;
// overflow -> flag). Sound: true argmax always inserted, never pruned.
#define SIMK_BM 128
#define SIMK_BN 128

__global__ __launch_bounds__(256, 3) void k_sim_hh(
    const _Float16* __restrict__ Apack,  // token rows: 1024 halves = hi|lo
    const _Float16* __restrict__ Bhi, float* __restrict__ pv,
    float4* __restrict__ cv, int4* __restrict__ cn, int* __restrict__ cflag) {
  __shared__ __align__(16) float sC[128 * 65];  // 33280 B; staging aliased
  _Float16* sAh = (_Float16*)sC;
  _Float16* sBh = sAh + 128 * LDH;

  const int tid = threadIdx.x;
  const int w = tid >> 6, l = tid & 63;
  const int wm = w >> 1, wn = w & 1;
  const int lm = l & 31, lh = l >> 5;
  const int s = blockIdx.x & 1;
  const int tokbase = (blockIdx.x >> 1) * SIMK_BM;
  const int code0 = s * (NCODE / 2);
  const int srow0 = tid >> 2, sq = tid & 3;
  const int t_red = tid >> 1, h_red = tid & 1;

  float bestv = -2.0f;
  float cv0 = -1e38f, cv1 = -1e38f, cv2 = -1e38f, cv3 = -1e38f;
  int cn0 = 0, cn1 = 0, cn2 = 0, cn3 = 0;
  int ovf = 0;

  for (int nt = 0; nt < NCODE / 2; nt += SIMK_BN) {
    f32x16 aHH[2][2];
#pragma unroll
    for (int mb = 0; mb < 2; ++mb)
#pragma unroll
      for (int nb = 0; nb < 2; ++nb) aHH[mb][nb] = (f32x16)0.0f;
    for (int ks = 0; ks < DIM; ks += 32) {
      __syncthreads();
#pragma unroll
      for (int i = 0; i < 2; ++i) {
        int row = srow0 + i * 64;
        *(f16x8*)(&sAh[row * LDH + sq * 8]) = *(const f16x8*)(
            Apack + (size_t)(tokbase + row) * 1024 + ks + sq * 8);
        *(f16x8*)(&sBh[row * LDH + sq * 8]) = *(const f16x8*)(
            Bhi + (size_t)(code0 + nt + row) * DIM + ks + sq * 8);
      }
      __syncthreads();
#pragma unroll
      for (int c = 0; c < 2; ++c) {
        const int ko = c * 16 + lh * 8;
        f16x8 ah[2], bh[2];
#pragma unroll
        for (int mb = 0; mb < 2; ++mb)
          ah[mb] = *(const f16x8*)(&sAh[(wm * 64 + mb * 32 + lm) * LDH + ko]);
#pragma unroll
        for (int nb = 0; nb < 2; ++nb)
          bh[nb] = *(const f16x8*)(&sBh[(wn * 64 + nb * 32 + lm) * LDH + ko]);
#pragma unroll
        for (int mb = 0; mb < 2; ++mb)
#pragma unroll
          for (int nb = 0; nb < 2; ++nb)
            aHH[mb][nb] = __builtin_amdgcn_mfma_f32_32x32x16_f16(
                ah[mb], bh[nb], aHH[mb][nb], 0, 0, 0);
      }
    }
    // epilogue: two n-halves through LDS (aliased over staging region)
#pragma unroll
    for (int p = 0; p < 2; ++p) {
      __syncthreads();
      if (wn == p) {
#pragma unroll
        for (int mb = 0; mb < 2; ++mb)
#pragma unroll
          for (int nb = 0; nb < 2; ++nb) {
            int nl = nb * 32 + lm;
#pragma unroll
            for (int r = 0; r < 16; ++r) {
              int m = wm * 64 + mb * 32 + (r & 3) + 8 * (r >> 2) + 4 * lh;
              sC[m * 65 + nl] = aHH[mb][nb][r];
            }
          }
      }
      __syncthreads();
      const float* rowp = &sC[t_red * 65 + h_red * 32];
      int nbase = code0 + nt + p * 64 + h_red * 32;
#pragma unroll
      for (int i = 0; i < 32; ++i) {
        float v = rowp[i];
        if (v >= bestv - MARGIN) {  // covers new-best too
          int n = nbase + i;
          if (v > bestv) {
            bestv = v;
            float th = v - MARGIN;
            if (cv0 < th) cv0 = -1e38f;
            if (cv1 < th) cv1 = -1e38f;
            if (cv2 < th) cv2 = -1e38f;
            if (cv3 < th) cv3 = -1e38f;
          }
          if (cv0 <= -1e37f) { cv0 = v; cn0 = n; }
          else if (cv1 <= -1e37f) { cv1 = v; cn1 = n; }
          else if (cv2 <= -1e37f) { cv2 = v; cn2 = n; }
          else if (cv3 <= -1e37f) { cv3 = v; cn3 = n; }
          else ovf = 1;
        }
      }
    }
  }
  int q = ((tokbase + t_red) << 2) | (h_red << 1) | s;
  pv[q] = bestv;
  cv[q] = make_float4(cv0, cv1, cv2, cv3);
  cn[q] = make_int4(cn0, cn1, cn2, cn3);
  cflag[q] = ovf;
}

// ---------------- pass 2: exact refine over candidates ----------------
// One wave per token. count==1 -> certain. Else exact fp64 dots (hi+lo/2048
// reconstruction, 2^-22 accurate) over candidates; overflow -> full scan.
__global__ __launch_bounds__(256) void k_refine(
    const _Float16* __restrict__ Apack, const _Float16* __restrict__ Bhi,
    const _Float16* __restrict__ Blo, const float* __restrict__ pv,
    const float4* __restrict__ cv, const int4* __restrict__ cn,
    const int* __restrict__ cflag, int* __restrict__ idx,
    float* __restrict__ idxf) {
  const int lane = threadIdx.x & 63;
  const int tok = blockIdx.x * 4 + (threadIdx.x >> 6);
  float gbest = -1e38f;
  int anyflag = 0;
  float cvv[16];
  int cnn[16];
#pragma unroll
  for (int r = 0; r < 4; ++r) {
    int q = (tok << 2) | r;
    gbest = fmaxf(gbest, pv[q]);
    anyflag |= cflag[q];
    float4 c4 = cv[q];
    int4 n4 = cn[q];
    cvv[r * 4 + 0] = c4.x; cnn[r * 4 + 0] = n4.x;
    cvv[r * 4 + 1] = c4.y; cnn[r * 4 + 1] = n4.y;
    cvv[r * 4 + 2] = c4.z; cnn[r * 4 + 2] = n4.z;
    cvv[r * 4 + 3] = c4.w; cnn[r * 4 + 3] = n4.w;
  }
  const float th = gbest - MARGIN;
  int cnt = 0, only = 0;
#pragma unroll
  for (int k = 0; k < 16; ++k)
    if (cvv[k] >= th) { cnt++; only = cnn[k]; }
  int winner;
  if (!anyflag && cnt == 1) {
    winner = only;
  } else if (!anyflag) {
    // exact fp64 eval of the candidate set (wave-parallel over dims)
    f16x8 zh = *(const f16x8*)(Apack + (size_t)tok * 1024 + lane * 8);
    f16x8 zl = *(const f16x8*)(Apack + (size_t)tok * 1024 + 512 + lane * 8);
    double za[8];
#pragma unroll
    for (int j = 0; j < 8; ++j)
      za[j] = (double)((float)zh[j]) + (double)((float)zl[j]) * (1.0 / 2048.0);
    double bsim = -1e30;
    int bn = 0x7fffffff;
#pragma unroll
    for (int k = 0; k < 16; ++k) {
      if (cvv[k] < th) continue;  // wave-uniform
      int n = cnn[k];
      f16x8 eh = *(const f16x8*)(Bhi + (size_t)n * DIM + lane * 8);
      f16x8 el = *(const f16x8*)(Blo + (size_t)n * DIM + lane * 8);
      double sacc = 0.0;
#pragma unroll
      for (int j = 0; j < 8; ++j)
        sacc += za[j] * ((double)((float)eh[j]) +
                         (double)((float)el[j]) * (1.0 / 2048.0));
#pragma unroll
      for (int off = 32; off > 0; off >>= 1) sacc += __shfl_xor(sacc, off, 64);
      if (sacc > bsim || (sacc == bsim && n < bn)) { bsim = sacc; bn = n; }
    }
    winner = bn;
  } else {
    // rare overflow: exact scan of all codes, lane-strided
    double bsim = -1e30;
    int bn = 0x7fffffff;
    for (int n = lane; n < NCODE; n += 64) {
      double sacc = 0.0;
      for (int d8 = 0; d8 < DIM; d8 += 8) {
        f16x8 zh2 = *(const f16x8*)(Apack + (size_t)tok * 1024 + d8);
        f16x8 zl2 = *(const f16x8*)(Apack + (size_t)tok * 1024 + 512 + d8);
        f16x8 eh = *(const f16x8*)(Bhi + (size_t)n * DIM + d8);
        f16x8 el = *(const f16x8*)(Blo + (size_t)n * DIM + d8);
#pragma unroll
        for (int j = 0; j < 8; ++j) {
          double a = (double)((float)zh2[j]) +
                     (double)((float)zl2[j]) * (1.0 / 2048.0);
          double b = (double)((float)eh[j]) +
                     (double)((float)el[j]) * (1.0 / 2048.0);
          sacc += a * b;
        }
      }
      if (sacc > bsim) { bsim = sacc; bn = n; }  // ascending n per lane
    }
#pragma unroll
    for (int off = 32; off > 0; off >>= 1) {
      double ovv = __shfl_xor(bsim, off, 64);
      int on = __shfl_xor(bn, off, 64);
      if (ovv > bsim || (ovv == bsim && on < bn)) { bsim = ovv; bn = on; }
    }
    winner = bn;
  }
  if (lane == 0) {
    idx[tok] = winner;
    idxf[tok] = (float)winner;
  }
}

extern "C" void kernel_launch(void* const* d_in, const int* in_sizes, int n_in,
                              void* d_out, int out_size, void* d_ws,
                              size_t ws_size, hipStream_t stream) {
  const float* z = (const float*)d_in[0];
  // d_in[1] = mask, unused
  const float* W_in = (const float*)d_in[2];
  const float* b_in = (const float*)d_in[3];
  const float* W_out = (const float*)d_in[4];
  const float* b_out = (const float*)d_in[5];
  const float* emb = (const float*)d_in[6];

  float* out = (float*)d_out;
  float* zq = out;                           // 32768*512 fp32 (final output)
  float* idxf = out + (size_t)BS_TOK * DIM;  // 32768 fp32 indices

  // ws: embhi|emblo|winhi|winlo|wouthi|woutlo|pv|cv|cn|cflag|idx  (~12 MB)
  _Float16* embhi = (_Float16*)d_ws;
  _Float16* emblo = embhi + (size_t)NCODE * DIM;
  _Float16* winhi = emblo + (size_t)NCODE * DIM;
  _Float16* winlo = winhi + (size_t)DIM * DIM;
  _Float16* wouthi = winlo + (size_t)DIM * DIM;
  _Float16* woutlo = wouthi + (size_t)DIM * DIM;
  float* pv = (float*)(woutlo + (size_t)DIM * DIM);  // 4*BS_TOK floats
  float4* cvb = (float4*)(pv + 4 * (size_t)BS_TOK);  // 4*BS_TOK float4
  int4* cnb = (int4*)(cvb + 4 * (size_t)BS_TOK);     // 4*BS_TOK int4
  int* cflag = (int*)(cnb + 4 * (size_t)BS_TOK);     // 4*BS_TOK ints
  int* idx = cflag + 4 * (size_t)BS_TOK;             // BS_TOK ints

  // zf fp32 lives in the zq region; then packed in-place to fp16 hi|lo rows
  float* zf = zq;
  _Float16* zf16 = (_Float16*)zf;  // row stride 1024 halves: [hi 512|lo 512]

  // 0) split weights
  k_split_w<<<DIM * DIM / 1024, 256, 0, stream>>>(W_in, winhi, winlo);
  k_split_w<<<DIM * DIM / 1024, 256, 0, stream>>>(W_out, wouthi, woutlo);
  // 1) normalize + split codebook rows -> ws
  k_rownorm_split<<<NCODE, 256, 0, stream>>>(emb, embhi, emblo, DIM);
  // 2) zf = z @ W_in^T + b_in (MFMA fp16-split, A converted on the fly)
  k_gemm_mfma_in<<<dim3(DIM / 128, BS_TOK / 128), 256, 0, stream>>>(
      z, winhi, winlo, b_in, zf);
  // 3) normalize zf rows, split to fp16 hi/lo IN-PLACE (packed rows)
  k_rownorm_split<<<BS_TOK, 256, 0, stream>>>(zf, zf16, zf16 + 512, 1024);
  // 4) hh-only similarity + candidate filter
  k_sim_hh<<<(BS_TOK / SIMK_BM) * 2, 256, 0, stream>>>(zf16, embhi, pv, cvb,
                                                       cnb, cflag);
  // 5) exact refine -> idx (ws) + idxf (d_out)
  k_refine<<<BS_TOK / 4, 256, 0, stream>>>(zf16, embhi, emblo, pv, cvb, cnb,
                                           cflag, idx, idxf);
  // 6) zq = emb_n[idx] @ W_out^T + b_out (+ straight-through), overwrites zf
  k_gemm_mfma_gather<<<dim3(DIM / 128, BS_TOK / 128), 256, 0, stream>>>(
      embhi, emblo, wouthi, woutlo, b_out, zq, idx, z);
}